// Round 6
// baseline (217.959 us; speedup 1.0000x reference)
//
#include <hip/hip_runtime.h>
#include <math.h>

#define NV 778
#define KROW 2334     // NV*3
#define KTOT 146      // 10 beta + 135 pose-feature + 1 const(template)
#define NCOL 1008     // 21 j * 16 jj * 3 c
#define NSTORE 12     // stored v-partials
#define VSP 33        // v-chunk (2 chunks per stored partial: 24*33=792>=778)
#define TPAD 101      // dirs tile row stride (101 = 5 mod 32, coprime -> conflict-free)

// ======================= k_pre: ALL batch-independent precompute =============
// bid <  48        : SJ[k][j][c], J0[j][c]
// bid <  384       : Q[j*16+jj] = sum_v Jreg*wgt
// bid <  384+21*12 : PKpart[s][k][j*48 + jj*3 + c] over 2 v-chunks of 33
__global__ __launch_bounds__(192) void k_pre(const float* __restrict__ shapedirs,
                                             const float* __restrict__ posedirs,
                                             const float* __restrict__ v_template,
                                             const float* __restrict__ Jreg,
                                             const float* __restrict__ wgt,
                                             float* __restrict__ SJ, float* __restrict__ J0,
                                             float* __restrict__ Q,  float* __restrict__ PKpart)
{
    __shared__ float tile[KTOT*TPAD];     // raw dirs rows: [k][3vv+c], 59 KB
    __shared__ float w2s[VSP*16];         // [vv][jj]
    const int bid = blockIdx.x;
    const int t = threadIdx.x;

    if (bid < 48) {
        if (t < 64) {
            const int j = bid / 3, c = bid % 3;
            float acc[11];
#pragma unroll
            for (int k = 0; k < 11; ++k) acc[k] = 0.f;
            for (int v = t; v < NV; v += 64) {
                const float jr = Jreg[v*21 + j];
                acc[10] += v_template[v*3 + c] * jr;
#pragma unroll
                for (int k = 0; k < 10; ++k)
                    acc[k] += shapedirs[(size_t)k*KROW + v*3 + c] * jr;
            }
#pragma unroll
            for (int k = 0; k < 11; ++k) {
                float s = acc[k];
#pragma unroll
                for (int off = 32; off >= 1; off >>= 1) s += __shfl_down(s, off, 64);
                acc[k] = s;
            }
            if (t == 0) {
#pragma unroll
                for (int k = 0; k < 10; ++k) SJ[k*48 + j*3 + c] = acc[k];
                J0[j*3 + c] = acc[10];
            }
        }
        return;
    }
    if (bid < 384) {
        if (t < 64) {
            const int m = bid - 48, j = m >> 4, jj = m & 15;
            float s = 0.f;
            for (int v = t; v < NV; v += 64)
                s += Jreg[v*21 + j] * wgt[v*16 + jj];
#pragma unroll
            for (int off = 32; off >= 1; off >>= 1) s += __shfl_down(s, off, 64);
            if (t == 0) Q[m] = s;
        }
        return;
    }

    // ---- PKpart: block = (j, s2) ----
    const int pb = bid - 384;            // 0..251
    const int j  = pb % 21;
    const int s2 = pb / 21;              // 0..11

    float acc[48];
#pragma unroll
    for (int q = 0; q < 48; ++q) acc[q] = 0.f;

    for (int h = 0; h < 2; ++h) {
        const int v0 = (2*s2 + h)*VSP;
        const int nvv = min(VSP, NV - v0);
        if (nvv <= 0) break;
        if (h) __syncthreads();          // previous chunk's readers done

        // stage dirs rows (coalesced along x) and W2 chunk
        const int xmax = 3*nvv;
        for (int idx = t; idx < KTOT*99; idx += 192) {
            const int k = idx / 99;
            const int x = idx - k*99;
            if (x < xmax) {
                const float* drow = (k < 10)  ? shapedirs + (size_t)k*KROW
                                  : (k < 145) ? posedirs + (size_t)(k-10)*KROW
                                              : v_template;
                tile[k*TPAD + x] = drow[3*v0 + x];
            }
        }
        for (int idx = t; idx < nvv*16; idx += 192) {
            const int vv = idx >> 4, jj = idx & 15;
            w2s[idx] = Jreg[(size_t)(v0+vv)*21 + j] * wgt[(size_t)(v0+vv)*16 + jj];
        }
        __syncthreads();

        if (t < KTOT) {
            const float* tr = tile + t*TPAD;
            for (int vv = 0; vv < nvv; ++vv) {
                const float d0 = tr[3*vv+0];
                const float d1 = tr[3*vv+1];
                const float d2 = tr[3*vv+2];
                const float4* wq = (const float4*)(w2s + vv*16);   // broadcast
                const float4 w0 = wq[0], w1 = wq[1], w2 = wq[2], w3 = wq[3];
                const float w[16] = {w0.x,w0.y,w0.z,w0.w, w1.x,w1.y,w1.z,w1.w,
                                     w2.x,w2.y,w2.z,w2.w, w3.x,w3.y,w3.z,w3.w};
#pragma unroll
                for (int jj = 0; jj < 16; ++jj) {
                    acc[jj*3+0] += d0*w[jj];
                    acc[jj*3+1] += d1*w[jj];
                    acc[jj*3+2] += d2*w[jj];
                }
            }
        }
    }

    if (t < KTOT) {
        float4* o = (float4*)(PKpart + ((size_t)s2*KTOT + t)*NCOL + j*48);
#pragma unroll
        for (int q = 0; q < 12; ++q)
            o[q] = make_float4(acc[4*q+0], acc[4*q+1], acc[4*q+2], acc[4*q+3]);
    }
}

// ======================= k_p3: reduce partials -> PK[146][1008] ==============
__global__ void k_p3(const float* __restrict__ PKpart, float* __restrict__ PK)
{
    const int idx = blockIdx.x*256 + threadIdx.x;
    if (idx < KTOT*NCOL) {
        float acc = 0.f;
#pragma unroll
        for (int s = 0; s < NSTORE; ++s)
            acc += PKpart[(size_t)s*KTOT*NCOL + idx];
        PK[idx] = acc;
    }
}

// ======================= k2: rodrigues + coefT + kinematic chain =============
__global__ __launch_bounds__(256) void k2_pose(const float* __restrict__ beta,
                                               const float* __restrict__ theta,
                                               const float* __restrict__ wrist,
                                               const float* __restrict__ hc,
                                               const float* __restrict__ hm,
                                               const float* __restrict__ SJ,
                                               const float* __restrict__ J0,
                                               float* __restrict__ coefT,
                                               float* __restrict__ A_g, int B, int cstride)
{
    __shared__ float Rs[16*144];
    __shared__ float cls[16*148];
    const int t = threadIdx.x;
    const int bl = t >> 4, i = t & 15;
    const int b = blockIdx.x*16 + bl;

    float r0, r1, r2;
    if (i == 0) {
        r0 = wrist[b*3+0]; r1 = wrist[b*3+1]; r2 = wrist[b*3+2];
#pragma unroll
        for (int k = 0; k < 10; ++k) cls[bl*148 + k] = beta[b*10 + k];
        cls[bl*148 + 145] = 1.0f;
    } else {
        const int col = (i-1)*3;
        float e0 = hm[col], e1 = hm[col+1], e2 = hm[col+2];
#pragma unroll
        for (int k = 0; k < 10; ++k) {
            const float th = theta[b*10 + k];
            e0 += th * hc[k*45 + col];
            e1 += th * hc[k*45 + col+1];
            e2 += th * hc[k*45 + col+2];
        }
        r0 = e0; r1 = e1; r2 = e2;
    }
    const float x_ = r0 + 1e-8f, y_ = r1 + 1e-8f, z_ = r2 + 1e-8f;
    const float angle = sqrtf(x_*x_ + y_*y_ + z_*z_);
    const float inv = 1.0f / angle;
    const float x = r0*inv, y = r1*inv, z = r2*inv;
    const float sn = sinf(angle), cs = cosf(angle);
    const float t1 = 1.0f - cs;
    float R[9];
    R[0] = 1.f - t1*(y*y + z*z);
    R[1] = -sn*z + t1*x*y;
    R[2] =  sn*y + t1*x*z;
    R[3] =  sn*z + t1*x*y;
    R[4] = 1.f - t1*(x*x + z*z);
    R[5] = -sn*x + t1*y*z;
    R[6] = -sn*y + t1*x*z;
    R[7] =  sn*x + t1*y*z;
    R[8] = 1.f - t1*(x*x + y*y);
#pragma unroll
    for (int q = 0; q < 9; ++q) Rs[bl*144 + i*9 + q] = R[q];
    if (i > 0) {
#pragma unroll
        for (int q = 0; q < 9; ++q)
            cls[bl*148 + 10 + (i-1)*9 + q] = R[q] - ((q==0||q==4||q==8) ? 1.f : 0.f);
    }
    __syncthreads();

    if (t < KTOT) {
        float tmp[16];
#pragma unroll
        for (int m = 0; m < 16; ++m) tmp[m] = cls[m*148 + t];
        float4* dst = (float4*)(coefT + (size_t)t*cstride + blockIdx.x*16);
        dst[0] = make_float4(tmp[0],  tmp[1],  tmp[2],  tmp[3]);
        dst[1] = make_float4(tmp[4],  tmp[5],  tmp[6],  tmp[7]);
        dst[2] = make_float4(tmp[8],  tmp[9],  tmp[10], tmp[11]);
        dst[3] = make_float4(tmp[12], tmp[13], tmp[14], tmp[15]);
    }

    if (t < 16) {
        const int b2 = blockIdx.x*16 + t;
        float bt[10];
#pragma unroll
        for (int k = 0; k < 10; ++k) bt[k] = beta[b2*10 + k];
        const float* Rb = Rs + t*144;
        float4* Ab = (float4*)(A_g + (size_t)b2*192);

        auto jointJ = [&](int j, float* o) {
            float j0 = J0[j*3+0], j1 = J0[j*3+1], j2 = J0[j*3+2];
#pragma unroll
            for (int k = 0; k < 10; ++k) {
                j0 += bt[k] * SJ[k*48 + j*3 + 0];
                j1 += bt[k] * SJ[k*48 + j*3 + 1];
                j2 += bt[k] * SJ[k*48 + j*3 + 2];
            }
            o[0] = j0; o[1] = j1; o[2] = j2;
        };

        float G0R[9], J0v[3];
#pragma unroll
        for (int q = 0; q < 9; ++q) G0R[q] = Rb[q];
        jointJ(0, J0v);
#pragma unroll
        for (int r = 0; r < 3; ++r) {
            const float at = J0v[r] - (G0R[r*3+0]*J0v[0] + G0R[r*3+1]*J0v[1] + G0R[r*3+2]*J0v[2]);
            Ab[r] = make_float4(G0R[r*3+0], G0R[r*3+1], G0R[r*3+2], at);
        }
        for (int ch = 0; ch < 5; ++ch) {
            float GpR[9], Gpt[3], Jp[3];
#pragma unroll
            for (int q = 0; q < 9; ++q) GpR[q] = G0R[q];
            Gpt[0]=J0v[0]; Gpt[1]=J0v[1]; Gpt[2]=J0v[2];
            Jp[0]=J0v[0];  Jp[1]=J0v[1];  Jp[2]=J0v[2];
            for (int s = 0; s < 3; ++s) {
                const int j = ch*3 + 1 + s;
                float Rl[9];
                const float* Rj = Rb + j*9;
#pragma unroll
                for (int q = 0; q < 9; ++q) Rl[q] = Rj[q];
                float Jc[3];
                jointJ(j, Jc);
                const float tl0 = Jc[0]-Jp[0], tl1 = Jc[1]-Jp[1], tl2 = Jc[2]-Jp[2];
                float GR[9], Gt[3];
#pragma unroll
                for (int r = 0; r < 3; ++r) {
#pragma unroll
                    for (int cc = 0; cc < 3; ++cc)
                        GR[r*3+cc] = GpR[r*3+0]*Rl[0*3+cc] + GpR[r*3+1]*Rl[1*3+cc] + GpR[r*3+2]*Rl[2*3+cc];
                    Gt[r] = GpR[r*3+0]*tl0 + GpR[r*3+1]*tl1 + GpR[r*3+2]*tl2 + Gpt[r];
                }
#pragma unroll
                for (int r = 0; r < 3; ++r) {
                    const float at = Gt[r] - (GR[r*3+0]*Jc[0] + GR[r*3+1]*Jc[1] + GR[r*3+2]*Jc[2]);
                    Ab[j*3 + r] = make_float4(GR[r*3+0], GR[r*3+1], GR[r*3+2], at);
                }
#pragma unroll
                for (int q = 0; q < 9; ++q) GpR[q] = GR[q];
                Gpt[0]=Gt[0]; Gpt[1]=Gt[1]; Gpt[2]=Gt[2];
                Jp[0]=Jc[0];  Jp[1]=Jc[1];  Jp[2]=Jc[2];
            }
        }
    }
}

// ======================= k3: P-GEMM + fused joint epilogue ===================
// grid (B/256, 21), 256 thr. Wave qg owns cols [12qg,12qg+12) (jj 4qg..4qg+3);
// thread owns 4 batches {b0+lg+64*bi}. Per k: 3 broadcast ds_read_b128 feed
// 48 FMA/lane (VALU-bound 96:36) + 4 coalesced b32 coef loads.
// Epilogue: per-wave 4-jj joint partials, 13-padded LDS exchange.
__global__ __launch_bounds__(256) void k3_gemm(const float* __restrict__ coefT,
                                               const float* __restrict__ PK,
                                               const float* __restrict__ A_g,
                                               const float* __restrict__ Q,
                                               float* __restrict__ out, int B, int cstride)
{
    __shared__ float pks[KTOT*48];       // 28 KB
    __shared__ float pex[256*13];        // 13.3 KB, pad 13 -> conflict-free
    const int t  = threadIdx.x;
    const int b0 = blockIdx.x * 256;
    const int j  = blockIdx.y;
    const int qg = t >> 6;
    const int lg = t & 63;

    for (int idx = t; idx < KTOT*48; idx += 256) {
        const int k = idx / 48, x = idx - k*48;
        pks[idx] = PK[(size_t)k*NCOL + j*48 + x];
    }
    __syncthreads();

    float acc[4][12];
#pragma unroll
    for (int bi = 0; bi < 4; ++bi)
#pragma unroll
        for (int r = 0; r < 12; ++r) acc[bi][r] = 0.f;

    const float* cb = coefT + b0 + lg;
    const float* pw = pks + 12*qg;

#pragma unroll 2
    for (int k = 0; k < KTOT; ++k) {
        const float c0 = cb[(size_t)k*cstride];
        const float c1 = cb[(size_t)k*cstride + 64];
        const float c2 = cb[(size_t)k*cstride + 128];
        const float c3 = cb[(size_t)k*cstride + 192];
        const float4 p0 = *(const float4*)(pw + k*48);      // broadcast
        const float4 p1 = *(const float4*)(pw + k*48 + 4);
        const float4 p2 = *(const float4*)(pw + k*48 + 8);
        const float p[12] = {p0.x,p0.y,p0.z,p0.w, p1.x,p1.y,p1.z,p1.w, p2.x,p2.y,p2.z,p2.w};
#pragma unroll
        for (int r = 0; r < 12; ++r) {
            acc[0][r] += p[r]*c0;
            acc[1][r] += p[r]*c1;
            acc[2][r] += p[r]*c2;
            acc[3][r] += p[r]*c3;
        }
    }

    const float* Qj = Q + j*16 + 4*qg;   // uniform
#pragma unroll
    for (int bi = 0; bi < 4; ++bi) {
        const int b = b0 + lg + 64*bi;
        const float4* Ab = ((const float4*)A_g) + (size_t)b*48 + 12*qg;
        float jx = 0.f, jy = 0.f, jz = 0.f;
#pragma unroll
        for (int l = 0; l < 4; ++l) {
            const float4 a0 = Ab[l*3+0];
            const float4 a1 = Ab[l*3+1];
            const float4 a2 = Ab[l*3+2];
            const float qv = Qj[l];
            const float px = acc[bi][l*3+0], py = acc[bi][l*3+1], pz = acc[bi][l*3+2];
            jx += a0.x*px + a0.y*py + a0.z*pz + a0.w*qv;
            jy += a1.x*px + a1.y*py + a1.z*pz + a1.w*qv;
            jz += a2.x*px + a2.y*py + a2.z*pz + a2.w*qv;
        }
        const int bloc = lg + 64*bi;
        pex[bloc*13 + qg*3 + 0] = jx;
        pex[bloc*13 + qg*3 + 1] = jy;
        pex[bloc*13 + qg*3 + 2] = jz;
    }
    __syncthreads();

    {
        const float* pr = pex + t*13;
        const float jx = pr[0] + pr[3] + pr[6] + pr[9];
        const float jy = pr[1] + pr[4] + pr[7] + pr[10];
        const float jz = pr[2] + pr[5] + pr[8] + pr[11];
        float* op = out + (size_t)(b0 + t)*63 + j*3;
        op[0] = jx; op[1] = jy; op[2] = jz;
    }
}

// ============================================================================
extern "C" void kernel_launch(void* const* d_in, const int* in_sizes, int n_in,
                              void* d_out, int out_size, void* d_ws, size_t ws_size,
                              hipStream_t stream) {
    (void)n_in; (void)out_size; (void)ws_size;
    const float* beta       = (const float*)d_in[0];
    const float* theta      = (const float*)d_in[1];
    const float* wrist      = (const float*)d_in[2];
    const float* v_template = (const float*)d_in[3];
    const float* shapedirs  = (const float*)d_in[4];
    const float* posedirs   = (const float*)d_in[5];
    const float* Jreg       = (const float*)d_in[6];
    const float* hc         = (const float*)d_in[7];
    const float* hm         = (const float*)d_in[8];
    const float* wgt        = (const float*)d_in[9];
    float* out = (float*)d_out;
    const int B = in_sizes[0] / 10;
    const int cstride = B + 64;          // dodge L1 set aliasing on 32KB strides

    float* ws = (float*)d_ws;
    size_t off = 0;
    auto alloc = [&](size_t n) { float* p = ws + off; off = (off + n + 63) & ~(size_t)63; return p; };
    float* SJ     = alloc(480);
    float* J0     = alloc(48);
    float* Q      = alloc(336);
    float* PKpart = alloc((size_t)NSTORE*KTOT*NCOL);
    float* PK     = alloc((size_t)KTOT*NCOL);
    float* coefT  = alloc((size_t)KTOT*cstride);
    float* A_g    = alloc((size_t)B*192);

    k_pre<<<384 + 21*NSTORE, 192, 0, stream>>>(shapedirs, posedirs, v_template,
                                               Jreg, wgt, SJ, J0, Q, PKpart);
    k2_pose<<<(B + 15)/16, 256, 0, stream>>>(beta, theta, wrist, hc, hm, SJ, J0,
                                             coefT, A_g, B, cstride);
    k_p3<<<(KTOT*NCOL + 255)/256, 256, 0, stream>>>(PKpart, PK);
    k3_gemm<<<dim3(B/256, 21), 256, 0, stream>>>(coefT, PK, A_g, Q, out, B, cstride);
}

// Round 7
// 211.089 us; speedup vs baseline: 1.0325x; 1.0325x over previous
//
#include <hip/hip_runtime.h>
#include <math.h>

#define NV 778
#define KROW 2334     // NV*3
#define KTOT 146      // 10 beta + 135 pose-feature + 1 const(template)
#define NCOL 1008     // 21 j * 16 jj * 3 c
#define NSTORE 12     // stored v-partials
#define VSP2 65       // v per PKpart block (12*65=780 >= 778)

// ======================= kT: transpose dirsX -> dirsXT[2334][146] ============
// Classic LDS-tile transpose; 37 x-tiles x 3 k-tiles = 111 blocks.
__global__ __launch_bounds__(256) void kT(const float* __restrict__ shapedirs,
                                          const float* __restrict__ posedirs,
                                          const float* __restrict__ v_template,
                                          float* __restrict__ dirsXT)
{
    __shared__ float tl[64][65];
    const int bx = blockIdx.x % 37;
    const int bk = blockIdx.x / 37;
    const int x0 = bx*64, k0 = bk*64;
    const int tx = threadIdx.x & 63, ty = threadIdx.x >> 6;
#pragma unroll 4
    for (int i = 0; i < 16; ++i) {
        const int r = ty*16 + i;
        const int kk = k0 + r, xx = x0 + tx;
        if (kk < KTOT && xx < KROW) {
            const float* drow = (kk < 10)  ? shapedirs + (size_t)kk*KROW
                              : (kk < 145) ? posedirs + (size_t)(kk-10)*KROW
                                           : v_template;
            tl[r][tx] = drow[xx];
        }
    }
    __syncthreads();
#pragma unroll 4
    for (int i = 0; i < 16; ++i) {
        const int xr = ty*16 + i;
        const int xx = x0 + xr, kk = k0 + tx;
        if (xx < KROW && kk < KTOT)
            dirsXT[(size_t)xx*KTOT + kk] = tl[tx][xr];
    }
}

// ======================= k_pre: batch-independent precompute =================
// bid < 48  : SJ[k][j][c], J0[j][c]
// bid < 50  : Q[j*16+jj] (2 blocks, lane = (j,jj))
// else      : PKpart[s][k][j*48 + h*24 + jjj*3 + c], 504 blocks (j, h, s)
__global__ __launch_bounds__(192) void k_pre(const float* __restrict__ shapedirs,
                                             const float* __restrict__ v_template,
                                             const float* __restrict__ dirsXT,
                                             const float* __restrict__ Jreg,
                                             const float* __restrict__ wgt,
                                             float* __restrict__ SJ, float* __restrict__ J0,
                                             float* __restrict__ Q,  float* __restrict__ PKpart)
{
    __shared__ float w2h[VSP2*8];     // 2 KB
    const int bid = blockIdx.x;
    const int t = threadIdx.x;

    if (bid < 48) {
        if (t < 64) {
            const int j = bid / 3, c = bid % 3;
            float acc[11];
#pragma unroll
            for (int k = 0; k < 11; ++k) acc[k] = 0.f;
            for (int v = t; v < NV; v += 64) {
                const float jr = Jreg[v*21 + j];
                acc[10] += v_template[v*3 + c] * jr;
#pragma unroll
                for (int k = 0; k < 10; ++k)
                    acc[k] += shapedirs[(size_t)k*KROW + v*3 + c] * jr;
            }
#pragma unroll
            for (int k = 0; k < 11; ++k) {
                float s = acc[k];
#pragma unroll
                for (int off = 32; off >= 1; off >>= 1) s += __shfl_down(s, off, 64);
                acc[k] = s;
            }
            if (t == 0) {
#pragma unroll
                for (int k = 0; k < 10; ++k) SJ[k*48 + j*3 + c] = acc[k];
                J0[j*3 + c] = acc[10];
            }
        }
        return;
    }
    if (bid < 50) {
        const int m = (bid - 48)*192 + t;
        if (m < 336) {
            const int j = m >> 4, jj = m & 15;
            float s = 0.f;
#pragma unroll 4
            for (int v = 0; v < NV; ++v)
                s += Jreg[v*21 + j] * wgt[v*16 + jj];
            Q[m] = s;
        }
        return;
    }

    // ---- PKpart: block = (j, h, s) ----
    const int pb = bid - 50;             // 0..503
    const int j  = pb % 21;
    const int h  = (pb / 21) & 1;        // jj half
    const int s  = pb / 42;              // 0..11
    const int v0 = s*VSP2;
    const int nvv = min(VSP2, NV - v0);

    for (int idx = t; idx < nvv*8; idx += 192) {
        const int vv = idx >> 3, jjj = idx & 7;
        w2h[idx] = Jreg[(size_t)(v0+vv)*21 + j] * wgt[(size_t)(v0+vv)*16 + h*8 + jjj];
    }
    __syncthreads();

    if (t < KTOT) {
        float acc[24];
#pragma unroll
        for (int q = 0; q < 24; ++q) acc[q] = 0.f;
        const float* dcol = dirsXT + t;
#pragma unroll 2
        for (int vv = 0; vv < nvv; ++vv) {
            const size_t xb = (size_t)3*(v0+vv)*KTOT;
            const float d0 = dcol[xb];
            const float d1 = dcol[xb + KTOT];
            const float d2 = dcol[xb + 2*KTOT];
            const float4 wa = *(const float4*)(w2h + vv*8);      // broadcast
            const float4 wb = *(const float4*)(w2h + vv*8 + 4);
            const float w[8] = {wa.x,wa.y,wa.z,wa.w, wb.x,wb.y,wb.z,wb.w};
#pragma unroll
            for (int q = 0; q < 8; ++q) {
                acc[q*3+0] += d0*w[q];
                acc[q*3+1] += d1*w[q];
                acc[q*3+2] += d2*w[q];
            }
        }
        float4* o = (float4*)(PKpart + ((size_t)s*KTOT + t)*NCOL + j*48 + h*24);
#pragma unroll
        for (int q = 0; q < 6; ++q)
            o[q] = make_float4(acc[4*q+0], acc[4*q+1], acc[4*q+2], acc[4*q+3]);
    }
}

// ======================= k_p3: reduce partials -> PK[146][1008] ==============
__global__ void k_p3(const float* __restrict__ PKpart, float* __restrict__ PK)
{
    const int idx = blockIdx.x*256 + threadIdx.x;
    if (idx < KTOT*NCOL) {
        float acc = 0.f;
#pragma unroll
        for (int s = 0; s < NSTORE; ++s)
            acc += PKpart[(size_t)s*KTOT*NCOL + idx];
        PK[idx] = acc;
    }
}

// ======================= k2: rodrigues + coefT + kinematic chain =============
__global__ __launch_bounds__(256) void k2_pose(const float* __restrict__ beta,
                                               const float* __restrict__ theta,
                                               const float* __restrict__ wrist,
                                               const float* __restrict__ hc,
                                               const float* __restrict__ hm,
                                               const float* __restrict__ SJ,
                                               const float* __restrict__ J0,
                                               float* __restrict__ coefT,
                                               float* __restrict__ A_g, int B, int cstride)
{
    __shared__ float Rs[16*144];
    __shared__ float cls[16*148];
    const int t = threadIdx.x;
    const int bl = t >> 4, i = t & 15;
    const int b = blockIdx.x*16 + bl;

    float r0, r1, r2;
    if (i == 0) {
        r0 = wrist[b*3+0]; r1 = wrist[b*3+1]; r2 = wrist[b*3+2];
#pragma unroll
        for (int k = 0; k < 10; ++k) cls[bl*148 + k] = beta[b*10 + k];
        cls[bl*148 + 145] = 1.0f;
    } else {
        const int col = (i-1)*3;
        float e0 = hm[col], e1 = hm[col+1], e2 = hm[col+2];
#pragma unroll
        for (int k = 0; k < 10; ++k) {
            const float th = theta[b*10 + k];
            e0 += th * hc[k*45 + col];
            e1 += th * hc[k*45 + col+1];
            e2 += th * hc[k*45 + col+2];
        }
        r0 = e0; r1 = e1; r2 = e2;
    }
    const float x_ = r0 + 1e-8f, y_ = r1 + 1e-8f, z_ = r2 + 1e-8f;
    const float angle = sqrtf(x_*x_ + y_*y_ + z_*z_);
    const float inv = 1.0f / angle;
    const float x = r0*inv, y = r1*inv, z = r2*inv;
    const float sn = sinf(angle), cs = cosf(angle);
    const float t1 = 1.0f - cs;
    float R[9];
    R[0] = 1.f - t1*(y*y + z*z);
    R[1] = -sn*z + t1*x*y;
    R[2] =  sn*y + t1*x*z;
    R[3] =  sn*z + t1*x*y;
    R[4] = 1.f - t1*(x*x + z*z);
    R[5] = -sn*x + t1*y*z;
    R[6] = -sn*y + t1*x*z;
    R[7] =  sn*x + t1*y*z;
    R[8] = 1.f - t1*(x*x + y*y);
#pragma unroll
    for (int q = 0; q < 9; ++q) Rs[bl*144 + i*9 + q] = R[q];
    if (i > 0) {
#pragma unroll
        for (int q = 0; q < 9; ++q)
            cls[bl*148 + 10 + (i-1)*9 + q] = R[q] - ((q==0||q==4||q==8) ? 1.f : 0.f);
    }
    __syncthreads();

    if (t < KTOT) {
        float tmp[16];
#pragma unroll
        for (int m = 0; m < 16; ++m) tmp[m] = cls[m*148 + t];
        float4* dst = (float4*)(coefT + (size_t)t*cstride + blockIdx.x*16);
        dst[0] = make_float4(tmp[0],  tmp[1],  tmp[2],  tmp[3]);
        dst[1] = make_float4(tmp[4],  tmp[5],  tmp[6],  tmp[7]);
        dst[2] = make_float4(tmp[8],  tmp[9],  tmp[10], tmp[11]);
        dst[3] = make_float4(tmp[12], tmp[13], tmp[14], tmp[15]);
    }

    if (t < 16) {
        const int b2 = blockIdx.x*16 + t;
        float bt[10];
#pragma unroll
        for (int k = 0; k < 10; ++k) bt[k] = beta[b2*10 + k];
        const float* Rb = Rs + t*144;
        float4* Ab = (float4*)(A_g + (size_t)b2*192);

        auto jointJ = [&](int j, float* o) {
            float j0 = J0[j*3+0], j1 = J0[j*3+1], j2 = J0[j*3+2];
#pragma unroll
            for (int k = 0; k < 10; ++k) {
                j0 += bt[k] * SJ[k*48 + j*3 + 0];
                j1 += bt[k] * SJ[k*48 + j*3 + 1];
                j2 += bt[k] * SJ[k*48 + j*3 + 2];
            }
            o[0] = j0; o[1] = j1; o[2] = j2;
        };

        float G0R[9], J0v[3];
#pragma unroll
        for (int q = 0; q < 9; ++q) G0R[q] = Rb[q];
        jointJ(0, J0v);
#pragma unroll
        for (int r = 0; r < 3; ++r) {
            const float at = J0v[r] - (G0R[r*3+0]*J0v[0] + G0R[r*3+1]*J0v[1] + G0R[r*3+2]*J0v[2]);
            Ab[r] = make_float4(G0R[r*3+0], G0R[r*3+1], G0R[r*3+2], at);
        }
        for (int ch = 0; ch < 5; ++ch) {
            float GpR[9], Gpt[3], Jp[3];
#pragma unroll
            for (int q = 0; q < 9; ++q) GpR[q] = G0R[q];
            Gpt[0]=J0v[0]; Gpt[1]=J0v[1]; Gpt[2]=J0v[2];
            Jp[0]=J0v[0];  Jp[1]=J0v[1];  Jp[2]=J0v[2];
            for (int s = 0; s < 3; ++s) {
                const int j = ch*3 + 1 + s;
                float Rl[9];
                const float* Rj = Rb + j*9;
#pragma unroll
                for (int q = 0; q < 9; ++q) Rl[q] = Rj[q];
                float Jc[3];
                jointJ(j, Jc);
                const float tl0 = Jc[0]-Jp[0], tl1 = Jc[1]-Jp[1], tl2 = Jc[2]-Jp[2];
                float GR[9], Gt[3];
#pragma unroll
                for (int r = 0; r < 3; ++r) {
#pragma unroll
                    for (int cc = 0; cc < 3; ++cc)
                        GR[r*3+cc] = GpR[r*3+0]*Rl[0*3+cc] + GpR[r*3+1]*Rl[1*3+cc] + GpR[r*3+2]*Rl[2*3+cc];
                    Gt[r] = GpR[r*3+0]*tl0 + GpR[r*3+1]*tl1 + GpR[r*3+2]*tl2 + Gpt[r];
                }
#pragma unroll
                for (int r = 0; r < 3; ++r) {
                    const float at = Gt[r] - (GR[r*3+0]*Jc[0] + GR[r*3+1]*Jc[1] + GR[r*3+2]*Jc[2]);
                    Ab[j*3 + r] = make_float4(GR[r*3+0], GR[r*3+1], GR[r*3+2], at);
                }
#pragma unroll
                for (int q = 0; q < 9; ++q) GpR[q] = GR[q];
                Gpt[0]=Gt[0]; Gpt[1]=Gt[1]; Gpt[2]=Gt[2];
                Jp[0]=Jc[0];  Jp[1]=Jc[1];  Jp[2]=Jc[2];
            }
        }
    }
}

// ======================= k3: P-GEMM + fused joint epilogue ===================
__global__ __launch_bounds__(256) void k3_gemm(const float* __restrict__ coefT,
                                               const float* __restrict__ PK,
                                               const float* __restrict__ A_g,
                                               const float* __restrict__ Q,
                                               float* __restrict__ out, int B, int cstride)
{
    __shared__ float pks[KTOT*48];       // 28 KB
    __shared__ float pex[256*13];        // 13.3 KB
    const int t  = threadIdx.x;
    const int b0 = blockIdx.x * 256;
    const int j  = blockIdx.y;
    const int qg = t >> 6;
    const int lg = t & 63;

    for (int idx = t; idx < KTOT*48; idx += 256) {
        const int k = idx / 48, x = idx - k*48;
        pks[idx] = PK[(size_t)k*NCOL + j*48 + x];
    }
    __syncthreads();

    float acc[4][12];
#pragma unroll
    for (int bi = 0; bi < 4; ++bi)
#pragma unroll
        for (int r = 0; r < 12; ++r) acc[bi][r] = 0.f;

    const float* cb = coefT + b0 + lg;
    const float* pw = pks + 12*qg;

#pragma unroll 2
    for (int k = 0; k < KTOT; ++k) {
        const float c0 = cb[(size_t)k*cstride];
        const float c1 = cb[(size_t)k*cstride + 64];
        const float c2 = cb[(size_t)k*cstride + 128];
        const float c3 = cb[(size_t)k*cstride + 192];
        const float4 p0 = *(const float4*)(pw + k*48);
        const float4 p1 = *(const float4*)(pw + k*48 + 4);
        const float4 p2 = *(const float4*)(pw + k*48 + 8);
        const float p[12] = {p0.x,p0.y,p0.z,p0.w, p1.x,p1.y,p1.z,p1.w, p2.x,p2.y,p2.z,p2.w};
#pragma unroll
        for (int r = 0; r < 12; ++r) {
            acc[0][r] += p[r]*c0;
            acc[1][r] += p[r]*c1;
            acc[2][r] += p[r]*c2;
            acc[3][r] += p[r]*c3;
        }
    }

    const float* Qj = Q + j*16 + 4*qg;
#pragma unroll
    for (int bi = 0; bi < 4; ++bi) {
        const int b = b0 + lg + 64*bi;
        const float4* Ab = ((const float4*)A_g) + (size_t)b*48 + 12*qg;
        float jx = 0.f, jy = 0.f, jz = 0.f;
#pragma unroll
        for (int l = 0; l < 4; ++l) {
            const float4 a0 = Ab[l*3+0];
            const float4 a1 = Ab[l*3+1];
            const float4 a2 = Ab[l*3+2];
            const float qv = Qj[l];
            const float px = acc[bi][l*3+0], py = acc[bi][l*3+1], pz = acc[bi][l*3+2];
            jx += a0.x*px + a0.y*py + a0.z*pz + a0.w*qv;
            jy += a1.x*px + a1.y*py + a1.z*pz + a1.w*qv;
            jz += a2.x*px + a2.y*py + a2.z*pz + a2.w*qv;
        }
        const int bloc = lg + 64*bi;
        pex[bloc*13 + qg*3 + 0] = jx;
        pex[bloc*13 + qg*3 + 1] = jy;
        pex[bloc*13 + qg*3 + 2] = jz;
    }
    __syncthreads();

    {
        const float* pr = pex + t*13;
        const float jx = pr[0] + pr[3] + pr[6] + pr[9];
        const float jy = pr[1] + pr[4] + pr[7] + pr[10];
        const float jz = pr[2] + pr[5] + pr[8] + pr[11];
        float* op = out + (size_t)(b0 + t)*63 + j*3;
        op[0] = jx; op[1] = jy; op[2] = jz;
    }
}

// ============================================================================
extern "C" void kernel_launch(void* const* d_in, const int* in_sizes, int n_in,
                              void* d_out, int out_size, void* d_ws, size_t ws_size,
                              hipStream_t stream) {
    (void)n_in; (void)out_size; (void)ws_size;
    const float* beta       = (const float*)d_in[0];
    const float* theta      = (const float*)d_in[1];
    const float* wrist      = (const float*)d_in[2];
    const float* v_template = (const float*)d_in[3];
    const float* shapedirs  = (const float*)d_in[4];
    const float* posedirs   = (const float*)d_in[5];
    const float* Jreg       = (const float*)d_in[6];
    const float* hc         = (const float*)d_in[7];
    const float* hm         = (const float*)d_in[8];
    const float* wgt        = (const float*)d_in[9];
    float* out = (float*)d_out;
    const int B = in_sizes[0] / 10;
    const int cstride = B + 64;

    float* ws = (float*)d_ws;
    size_t off = 0;
    auto alloc = [&](size_t n) { float* p = ws + off; off = (off + n + 63) & ~(size_t)63; return p; };
    float* SJ     = alloc(480);
    float* J0     = alloc(48);
    float* Q      = alloc(336);
    float* dirsXT = alloc((size_t)KROW*KTOT);
    float* PKpart = alloc((size_t)NSTORE*KTOT*NCOL);
    float* PK     = alloc((size_t)KTOT*NCOL);
    float* coefT  = alloc((size_t)KTOT*cstride);
    float* A_g    = alloc((size_t)B*192);

    kT<<<111, 256, 0, stream>>>(shapedirs, posedirs, v_template, dirsXT);
    k_pre<<<50 + 21*2*NSTORE, 192, 0, stream>>>(shapedirs, v_template, dirsXT,
                                                Jreg, wgt, SJ, J0, Q, PKpart);
    k2_pose<<<(B + 15)/16, 256, 0, stream>>>(beta, theta, wrist, hc, hm, SJ, J0,
                                             coefT, A_g, B, cstride);
    k_p3<<<(KTOT*NCOL + 255)/256, 256, 0, stream>>>(PKpart, PK);
    k3_gemm<<<dim3(B/256, 21), 256, 0, stream>>>(coefT, PK, A_g, Q, out, B, cstride);
}